// Round 12
// baseline (419.569 us; speedup 1.0000x reference)
//
#include <hip/hip_runtime.h>
#include <cmath>

#define DIM 1024
#define NHEADS 16
#define HDIM 64
#define NB 2
#define SEQ 2048
// M = NB*SEQ = 4096 rows through both GEMMs

typedef __bf16 bf16x8 __attribute__((ext_vector_type(8)));
typedef __bf16 bf16x4 __attribute__((ext_vector_type(4)));
typedef float f32x4 __attribute__((ext_vector_type(4)));

union Bf8 { bf16x8 v; __bf16 e[8]; unsigned short us[8]; };
union Bf4 { bf16x4 v; __bf16 e[4]; };
union Bf1 { __bf16 b; unsigned short u; };
union U4B { unsigned int u[4]; bf16x8 v; };

__device__ __forceinline__ void split_bf(float f, __bf16 &h, __bf16 &l) {
    h = (__bf16)f;
    l = (__bf16)(f - (float)h);
}
__device__ __forceinline__ unsigned short bfu(__bf16 b) { Bf1 c; c.b = b; return c.u; }

// ---------------------------------------------------------------------------
// Prepass: split an f32 array into hi/lo bf16 planes (full-ws path only).
// ---------------------------------------------------------------------------
__global__ __launch_bounds__(256) void split_f32(const float* __restrict__ in,
                                                 __bf16* __restrict__ hi,
                                                 __bf16* __restrict__ lo, int n4) {
    for (int i = blockIdx.x * blockDim.x + threadIdx.x; i < n4;
         i += gridDim.x * blockDim.x) {
        const float4 v = reinterpret_cast<const float4*>(in)[i];
        const float f[4] = {v.x, v.y, v.z, v.w};
        Bf4 h, l;
#pragma unroll
        for (int e = 0; e < 4; ++e) split_bf(f[e], h.e[e], l.e[e]);
        reinterpret_cast<bf16x4*>(hi)[i] = h.v;
        reinterpret_cast<bf16x4*>(lo)[i] = l.v;
    }
}

// ---------------------------------------------------------------------------
// Split-bf16 MFMA GEMM (NT) — UNCHANGED from validated r9.
// ---------------------------------------------------------------------------
template <bool SA, bool SB, bool SOUT, bool QSCALE, bool HAS_BIAS>
__global__ __launch_bounds__(256) void gemm_nt_mfma(
    const float* __restrict__ Af, const __bf16* __restrict__ Agh, const __bf16* __restrict__ Agl,
    const float* __restrict__ Bf, const __bf16* __restrict__ Bgh, const __bf16* __restrict__ Bgl,
    const float* __restrict__ bias,
    float* __restrict__ Cf, __bf16* __restrict__ Cgh, __bf16* __restrict__ Cgl,
    int M, int Nc, int K) {
    __shared__ __align__(16) __bf16 Ah[128][40];
    __shared__ __align__(16) __bf16 Al[128][40];
    __shared__ __align__(16) __bf16 Bh[128][40];
    __shared__ __align__(16) __bf16 Bl[128][40];

    const int nwg  = gridDim.x;
    const int orig = blockIdx.x;
    const int tile = (orig & 7) * (nwg >> 3) + (orig >> 3);
    const int gx   = Nc >> 7;
    const int m0   = (tile / gx) * 128;
    const int n0   = (tile % gx) * 128;

    const int t  = threadIdx.x;
    const int w  = t >> 6;
    const int l  = t & 63;
    const int wr = (w >> 1) * 64;
    const int wc = (w & 1) * 64;
    const int lr = l & 15;
    const int kg = l >> 4;

    const int srow = t >> 1;
    const int skh  = (t & 1) * 16;
    const size_t arow = (size_t)(m0 + srow) * K + skh;
    const size_t brow = (size_t)(n0 + srow) * K + skh;

    f32x4 acc[4][4] = {};

    for (int k0 = 0; k0 < K; k0 += 32) {
        float4 av[4], bv[4];
        bf16x8 sah[2], sal[2], sbh[2], sbl[2];
        if constexpr (SA) {
            sah[0] = *reinterpret_cast<const bf16x8*>(Agh + arow + k0);
            sah[1] = *reinterpret_cast<const bf16x8*>(Agh + arow + k0 + 8);
            sal[0] = *reinterpret_cast<const bf16x8*>(Agl + arow + k0);
            sal[1] = *reinterpret_cast<const bf16x8*>(Agl + arow + k0 + 8);
        } else {
#pragma unroll
            for (int i = 0; i < 4; ++i)
                av[i] = *reinterpret_cast<const float4*>(Af + arow + k0 + i * 4);
        }
        if constexpr (SB) {
            sbh[0] = *reinterpret_cast<const bf16x8*>(Bgh + brow + k0);
            sbh[1] = *reinterpret_cast<const bf16x8*>(Bgh + brow + k0 + 8);
            sbl[0] = *reinterpret_cast<const bf16x8*>(Bgl + brow + k0);
            sbl[1] = *reinterpret_cast<const bf16x8*>(Bgl + brow + k0 + 8);
        } else {
#pragma unroll
            for (int i = 0; i < 4; ++i)
                bv[i] = *reinterpret_cast<const float4*>(Bf + brow + k0 + i * 4);
        }
        __syncthreads();  // previous iteration done reading LDS

        if constexpr (SA) {
            *reinterpret_cast<bf16x8*>(&Ah[srow][skh])     = sah[0];
            *reinterpret_cast<bf16x8*>(&Ah[srow][skh + 8]) = sah[1];
            *reinterpret_cast<bf16x8*>(&Al[srow][skh])     = sal[0];
            *reinterpret_cast<bf16x8*>(&Al[srow][skh + 8]) = sal[1];
        } else {
#pragma unroll
            for (int half = 0; half < 2; ++half) {
                Bf8 hh, ll;
#pragma unroll
                for (int q = 0; q < 2; ++q) {
                    const float4 va = av[half * 2 + q];
                    const float fa[4] = {va.x, va.y, va.z, va.w};
#pragma unroll
                    for (int e = 0; e < 4; ++e)
                        split_bf(fa[e], hh.e[q * 4 + e], ll.e[q * 4 + e]);
                }
                *reinterpret_cast<bf16x8*>(&Ah[srow][skh + half * 8]) = hh.v;
                *reinterpret_cast<bf16x8*>(&Al[srow][skh + half * 8]) = ll.v;
            }
        }
        if constexpr (SB) {
            *reinterpret_cast<bf16x8*>(&Bh[srow][skh])     = sbh[0];
            *reinterpret_cast<bf16x8*>(&Bh[srow][skh + 8]) = sbh[1];
            *reinterpret_cast<bf16x8*>(&Bl[srow][skh])     = sbl[0];
            *reinterpret_cast<bf16x8*>(&Bl[srow][skh + 8]) = sbl[1];
        } else {
#pragma unroll
            for (int half = 0; half < 2; ++half) {
                Bf8 hh, ll;
#pragma unroll
                for (int q = 0; q < 2; ++q) {
                    const float4 vb = bv[half * 2 + q];
                    const float fb[4] = {vb.x, vb.y, vb.z, vb.w};
#pragma unroll
                    for (int e = 0; e < 4; ++e)
                        split_bf(fb[e], hh.e[q * 4 + e], ll.e[q * 4 + e]);
                }
                *reinterpret_cast<bf16x8*>(&Bh[srow][skh + half * 8]) = hh.v;
                *reinterpret_cast<bf16x8*>(&Bl[srow][skh + half * 8]) = ll.v;
            }
        }
        __syncthreads();  // tiles ready

        bf16x8 fah[4], fal[4], fbh[4], fbl[4];
#pragma unroll
        for (int mi = 0; mi < 4; ++mi) {
            fah[mi] = *reinterpret_cast<const bf16x8*>(&Ah[wr + mi * 16 + lr][kg * 8]);
            fal[mi] = *reinterpret_cast<const bf16x8*>(&Al[wr + mi * 16 + lr][kg * 8]);
        }
#pragma unroll
        for (int nj = 0; nj < 4; ++nj) {
            fbh[nj] = *reinterpret_cast<const bf16x8*>(&Bh[wc + nj * 16 + lr][kg * 8]);
            fbl[nj] = *reinterpret_cast<const bf16x8*>(&Bl[wc + nj * 16 + lr][kg * 8]);
        }
#pragma unroll
        for (int mi = 0; mi < 4; ++mi)
#pragma unroll
            for (int nj = 0; nj < 4; ++nj) {
                acc[mi][nj] = __builtin_amdgcn_mfma_f32_16x16x32_bf16(
                    fah[mi], fbh[nj], acc[mi][nj], 0, 0, 0);
                acc[mi][nj] = __builtin_amdgcn_mfma_f32_16x16x32_bf16(
                    fal[mi], fbh[nj], acc[mi][nj], 0, 0, 0);
                acc[mi][nj] = __builtin_amdgcn_mfma_f32_16x16x32_bf16(
                    fah[mi], fbl[nj], acc[mi][nj], 0, 0, 0);
            }
    }

    const int orw = kg * 4;
#pragma unroll
    for (int mi = 0; mi < 4; ++mi) {
#pragma unroll
        for (int r = 0; r < 4; ++r) {
            const int row = m0 + wr + mi * 16 + orw + r;
#pragma unroll
            for (int nj = 0; nj < 4; ++nj) {
                const int col = n0 + wc + nj * 16 + lr;
                float v = acc[mi][nj][r];
                if constexpr (SOUT) {
                    if constexpr (QSCALE) {
                        if (col < DIM) v *= 0.125f;   // fold attention 1/sqrt(64)
                    }
                    __bf16 hh, ll;
                    split_bf(v, hh, ll);
                    const size_t off = (size_t)row * Nc + col;
                    Cgh[off] = hh;
                    Cgl[off] = ll;
                } else {
                    if constexpr (HAS_BIAS) v += bias[col];
                    Cf[(size_t)row * Nc + col] = v;
                }
            }
        }
    }
}

// ---------------------------------------------------------------------------
// Fused flash attention, split-bf16 MFMA, SWAPPED-OPERAND form (r10).
//  * S^T = mfma(K, Q): identical register contents, C col = q-row (lane-local
//    softmax: 15 fmax in-reg + shfl_xor(16),(32); m/l are scalars per mi).
//  * P^T redistributed in-register to the PV B-fragment via 64 __shfl +
//    selects (derived & element-checked vs validated frag layouts):
//      lane(lr,kg) B-frag[ks] keys = ks*32+kg*8+j; source lane = lr+32*(kg&1)
//      (+16 for j>=4); nj = ks*2 + (kg>>1); r = j&3.
//  * O^T = mfma(V^T, P^T) — V reads unchanged; C row = dim, col = q-row.
//  * P32 LDS buffer DELETED -> LDS 36.9KB; launch_bounds(256,3) -> 3 blk/CU.
// ---------------------------------------------------------------------------
__global__ __launch_bounds__(256, 3) void attn_mfma(const __bf16* __restrict__ qkv_hi,
                                                    const __bf16* __restrict__ qkv_lo,
                                                    __bf16* __restrict__ o_hi,
                                                    __bf16* __restrict__ o_lo) {
    __shared__ __align__(16) __bf16 Khi[64][72];
    __shared__ __align__(16) __bf16 Klo[64][72];
    __shared__ __align__(16) __bf16 Vhi[64][72];   // [dim][key]
    __shared__ __align__(16) __bf16 Vlo[64][72];   // [dim][key]

    const int nwg  = gridDim.x;
    const int orig = blockIdx.x;
    const int tile = (orig & 7) * (nwg >> 3) + (orig >> 3);
    const int qt = tile & 15;
    const int h  = (tile >> 4) & 15;
    const int b  = tile >> 8;

    const int t  = threadIdx.x;
    const int w  = t >> 6;
    const int l  = t & 63;
    const int lr = l & 15;
    const int kg = l >> 4;
    const int wq = w * 32;

    const size_t bbase = (size_t)b * SEQ * 3 * DIM;
    const int    hoff  = h * HDIM;

    // ---- Q fragments: direct pre-split loads (already scaled by 1/8)
    bf16x8 qfh[2][2], qfl[2][2];
#pragma unroll
    for (int mi = 0; mi < 2; ++mi) {
#pragma unroll
        for (int ks = 0; ks < 2; ++ks) {
            const size_t qoff = bbase +
                (size_t)(qt * 128 + wq + mi * 16 + lr) * (3 * DIM) + hoff + ks * 32 + kg * 8;
            qfh[mi][ks] = *reinterpret_cast<const bf16x8*>(qkv_hi + qoff);
            qfl[mi][ks] = *reinterpret_cast<const bf16x8*>(qkv_lo + qoff);
        }
    }

    // staging: K row-major (thread: key t>>2, 16 dims); V transposed
    const int skey = t >> 2;
    const int sd0  = (t & 3) * 16;
    const int vkp  = (t & 31) * 2;
    const int vd0  = (t >> 5) * 8;

    const size_t koff  = bbase + DIM + hoff + (size_t)skey * (3 * DIM) + sd0;
    const size_t voff0 = bbase + 2 * DIM + hoff + (size_t)(vkp + 0) * (3 * DIM) + vd0;
    const size_t voff1 = bbase + 2 * DIM + hoff + (size_t)(vkp + 1) * (3 * DIM) + vd0;
    const size_t kvstep = (size_t)64 * 3 * DIM;

    bf16x8 kr[4], vr[4];
    kr[0] = *reinterpret_cast<const bf16x8*>(qkv_hi + koff);
    kr[1] = *reinterpret_cast<const bf16x8*>(qkv_hi + koff + 8);
    kr[2] = *reinterpret_cast<const bf16x8*>(qkv_lo + koff);
    kr[3] = *reinterpret_cast<const bf16x8*>(qkv_lo + koff + 8);
    vr[0] = *reinterpret_cast<const bf16x8*>(qkv_hi + voff0);
    vr[1] = *reinterpret_cast<const bf16x8*>(qkv_hi + voff1);
    vr[2] = *reinterpret_cast<const bf16x8*>(qkv_lo + voff0);
    vr[3] = *reinterpret_cast<const bf16x8*>(qkv_lo + voff1);

    f32x4 oacc[2][4] = {};           // oacc[mi][njd][r]: dim=njd*16+kg*4+r, q=wq+mi*16+lr
    float mrow[2] = {-INFINITY, -INFINITY};
    float lrow[2] = {0.f, 0.f};

    // shuffle geometry (constants per lane)
    const int srcA  = (l & 15) | ((l & 16) << 1);   // lr + 32*(kg&1)
    const int srcB  = srcA + 16;
    const bool selHi = (l & 32) != 0;               // kg>>1

    for (int kt = 0; kt < SEQ / 64; ++kt) {
        __syncthreads();   // all waves done reading K/V of previous tile

        // ---- K tile: pure b128 copies
        *reinterpret_cast<bf16x8*>(&Khi[skey][sd0])     = kr[0];
        *reinterpret_cast<bf16x8*>(&Khi[skey][sd0 + 8]) = kr[1];
        *reinterpret_cast<bf16x8*>(&Klo[skey][sd0])     = kr[2];
        *reinterpret_cast<bf16x8*>(&Klo[skey][sd0 + 8]) = kr[3];
        // ---- V tile transposed: pack 2 keys per u32
        {
            Bf8 k0h, k1h, k0l, k1l;
            k0h.v = vr[0]; k1h.v = vr[1]; k0l.v = vr[2]; k1l.v = vr[3];
#pragma unroll
            for (int e = 0; e < 8; ++e) {
                *reinterpret_cast<unsigned int*>(&Vhi[vd0 + e][vkp]) =
                    (unsigned int)k0h.us[e] | ((unsigned int)k1h.us[e] << 16);
                *reinterpret_cast<unsigned int*>(&Vlo[vd0 + e][vkp]) =
                    (unsigned int)k0l.us[e] | ((unsigned int)k1l.us[e] << 16);
            }
        }
        __syncthreads();   // K/V ready

        // ---- prefetch next K/V tile
        if (kt < SEQ / 64 - 1) {
            const size_t kk = koff + (size_t)(kt + 1) * kvstep;
            const size_t v0 = voff0 + (size_t)(kt + 1) * kvstep;
            const size_t v1 = voff1 + (size_t)(kt + 1) * kvstep;
            kr[0] = *reinterpret_cast<const bf16x8*>(qkv_hi + kk);
            kr[1] = *reinterpret_cast<const bf16x8*>(qkv_hi + kk + 8);
            kr[2] = *reinterpret_cast<const bf16x8*>(qkv_lo + kk);
            kr[3] = *reinterpret_cast<const bf16x8*>(qkv_lo + kk + 8);
            vr[0] = *reinterpret_cast<const bf16x8*>(qkv_hi + v0);
            vr[1] = *reinterpret_cast<const bf16x8*>(qkv_hi + v1);
            vr[2] = *reinterpret_cast<const bf16x8*>(qkv_lo + v0);
            vr[3] = *reinterpret_cast<const bf16x8*>(qkv_lo + v1);
        }

        // ---- S^T = mfma(K, Q): sacc[mi][nj][r] = S[q=wq+mi*16+lr][key=nj*16+kg*4+r]
        f32x4 sacc[2][4] = {};
#pragma unroll
        for (int ks = 0; ks < 2; ++ks) {
#pragma unroll
            for (int nj = 0; nj < 4; ++nj) {
                const bf16x8 kh = *reinterpret_cast<const bf16x8*>(&Khi[nj * 16 + lr][ks * 32 + kg * 8]);
                const bf16x8 kl = *reinterpret_cast<const bf16x8*>(&Klo[nj * 16 + lr][ks * 32 + kg * 8]);
#pragma unroll
                for (int mi = 0; mi < 2; ++mi) {
                    sacc[mi][nj] = __builtin_amdgcn_mfma_f32_16x16x32_bf16(kh, qfh[mi][ks], sacc[mi][nj], 0, 0, 0);
                    sacc[mi][nj] = __builtin_amdgcn_mfma_f32_16x16x32_bf16(kl, qfh[mi][ks], sacc[mi][nj], 0, 0, 0);
                    sacc[mi][nj] = __builtin_amdgcn_mfma_f32_16x16x32_bf16(kh, qfl[mi][ks], sacc[mi][nj], 0, 0, 0);
                }
            }
        }

        // ---- lane-local online softmax + pack P^T (hi|lo pair words)
        unsigned int pkh[2][4][2], pkl[2][4][2];
#pragma unroll
        for (int mi = 0; mi < 2; ++mi) {
            float pm = -INFINITY;
#pragma unroll
            for (int nj = 0; nj < 4; ++nj)
#pragma unroll
                for (int r = 0; r < 4; ++r) pm = fmaxf(pm, sacc[mi][nj][r]);
            pm = fmaxf(pm, __shfl_xor(pm, 16));
            pm = fmaxf(pm, __shfl_xor(pm, 32));
            const float nm = fmaxf(mrow[mi], pm);
            float ls = 0.f;
#pragma unroll
            for (int nj = 0; nj < 4; ++nj)
#pragma unroll
                for (int r = 0; r < 4; ++r) {
                    const float p = __expf(sacc[mi][nj][r] - nm);
                    sacc[mi][nj][r] = p;
                    ls += p;
                }
            ls += __shfl_xor(ls, 16);
            ls += __shfl_xor(ls, 32);
            const float fac = __expf(mrow[mi] - nm);
            mrow[mi] = nm;
            lrow[mi] = lrow[mi] * fac + ls;
#pragma unroll
            for (int njd = 0; njd < 4; ++njd)
#pragma unroll
                for (int r = 0; r < 4; ++r) oacc[mi][njd][r] *= fac;
            // pack: pk[mi][nj][w] = keys (nj*16+kg*4+2w, +2w+1) as bf16 pair
#pragma unroll
            for (int nj = 0; nj < 4; ++nj) {
                __bf16 hh[4], ll[4];
#pragma unroll
                for (int r = 0; r < 4; ++r) split_bf(sacc[mi][nj][r], hh[r], ll[r]);
                pkh[mi][nj][0] = (unsigned int)bfu(hh[0]) | ((unsigned int)bfu(hh[1]) << 16);
                pkh[mi][nj][1] = (unsigned int)bfu(hh[2]) | ((unsigned int)bfu(hh[3]) << 16);
                pkl[mi][nj][0] = (unsigned int)bfu(ll[0]) | ((unsigned int)bfu(ll[1]) << 16);
                pkl[mi][nj][1] = (unsigned int)bfu(ll[2]) | ((unsigned int)bfu(ll[3]) << 16);
            }
        }

        // ---- O^T += mfma(V^T, P^T): gather P^T B-frags via shfl, then MFMA
#pragma unroll
        for (int ks = 0; ks < 2; ++ks) {
            bf16x8 pbh[2], pbl[2];
#pragma unroll
            for (int mi = 0; mi < 2; ++mi) {
                U4B gh, gl;
                {
                    const unsigned int a0 = (unsigned int)__shfl((int)pkh[mi][ks * 2][0], srcA);
                    const unsigned int a1 = (unsigned int)__shfl((int)pkh[mi][ks * 2 + 1][0], srcA);
                    const unsigned int b0 = (unsigned int)__shfl((int)pkh[mi][ks * 2][1], srcA);
                    const unsigned int b1 = (unsigned int)__shfl((int)pkh[mi][ks * 2 + 1][1], srcA);
                    const unsigned int c0 = (unsigned int)__shfl((int)pkh[mi][ks * 2][0], srcB);
                    const unsigned int c1 = (unsigned int)__shfl((int)pkh[mi][ks * 2 + 1][0], srcB);
                    const unsigned int d0 = (unsigned int)__shfl((int)pkh[mi][ks * 2][1], srcB);
                    const unsigned int d1 = (unsigned int)__shfl((int)pkh[mi][ks * 2 + 1][1], srcB);
                    gh.u[0] = selHi ? a1 : a0;
                    gh.u[1] = selHi ? b1 : b0;
                    gh.u[2] = selHi ? c1 : c0;
                    gh.u[3] = selHi ? d1 : d0;
                }
                {
                    const unsigned int a0 = (unsigned int)__shfl((int)pkl[mi][ks * 2][0], srcA);
                    const unsigned int a1 = (unsigned int)__shfl((int)pkl[mi][ks * 2 + 1][0], srcA);
                    const unsigned int b0 = (unsigned int)__shfl((int)pkl[mi][ks * 2][1], srcA);
                    const unsigned int b1 = (unsigned int)__shfl((int)pkl[mi][ks * 2 + 1][1], srcA);
                    const unsigned int c0 = (unsigned int)__shfl((int)pkl[mi][ks * 2][0], srcB);
                    const unsigned int c1 = (unsigned int)__shfl((int)pkl[mi][ks * 2 + 1][0], srcB);
                    const unsigned int d0 = (unsigned int)__shfl((int)pkl[mi][ks * 2][1], srcB);
                    const unsigned int d1 = (unsigned int)__shfl((int)pkl[mi][ks * 2 + 1][1], srcB);
                    gl.u[0] = selHi ? a1 : a0;
                    gl.u[1] = selHi ? b1 : b0;
                    gl.u[2] = selHi ? c1 : c0;
                    gl.u[3] = selHi ? d1 : d0;
                }
                pbh[mi] = gh.v;
                pbl[mi] = gl.v;
            }
#pragma unroll
            for (int njd = 0; njd < 4; ++njd) {
                const bf16x8 vh = *reinterpret_cast<const bf16x8*>(&Vhi[njd * 16 + lr][ks * 32 + kg * 8]);
                const bf16x8 vl = *reinterpret_cast<const bf16x8*>(&Vlo[njd * 16 + lr][ks * 32 + kg * 8]);
#pragma unroll
                for (int mi = 0; mi < 2; ++mi) {
                    oacc[mi][njd] = __builtin_amdgcn_mfma_f32_16x16x32_bf16(vh, pbh[mi], oacc[mi][njd], 0, 0, 0);
                    oacc[mi][njd] = __builtin_amdgcn_mfma_f32_16x16x32_bf16(vl, pbh[mi], oacc[mi][njd], 0, 0, 0);
                    oacc[mi][njd] = __builtin_amdgcn_mfma_f32_16x16x32_bf16(vh, pbl[mi], oacc[mi][njd], 0, 0, 0);
                }
            }
        }
    }

    // ---- epilogue: O^T frag -> O rows; normalize, split, write hi/lo planes
#pragma unroll
    for (int mi = 0; mi < 2; ++mi) {
        const float inv = 1.f / lrow[mi];
        const int grow = b * SEQ + qt * 128 + wq + mi * 16 + lr;
#pragma unroll
        for (int njd = 0; njd < 4; ++njd)
#pragma unroll
            for (int r = 0; r < 4; ++r) {
                const float v = oacc[mi][njd][r] * inv;
                __bf16 hh, ll;
                split_bf(v, hh, ll);
                const size_t off = (size_t)grow * DIM + hoff + njd * 16 + kg * 4 + r;
                o_hi[off] = hh;
                o_lo[off] = ll;
            }
    }
}

// ---------------------------------------------------------------------------
extern "C" void kernel_launch(void* const* d_in, const int* in_sizes, int n_in,
                              void* d_out, int out_size, void* d_ws, size_t ws_size,
                              hipStream_t stream) {
    const float* x      = (const float*)d_in[0];   // [2,2048,1024]
    const float* w_qkv  = (const float*)d_in[1];   // [3072,1024]
    const float* w_proj = (const float*)d_in[2];   // [1024,1024]
    const float* b_proj = (const float*)d_in[3];   // [1024]
    float* out = (float*)d_out;                    // [2,2048,1024]

    const int M = NB * SEQ;                        // 4096
    const size_t qkvN  = (size_t)M * 3 * DIM;
    const size_t obufN = (size_t)M * DIM;
    const size_t xN    = (size_t)M * DIM;
    const size_t wqN   = (size_t)(3 * DIM) * DIM;
    const size_t wpN   = (size_t)DIM * DIM;

    __bf16* p = (__bf16*)d_ws;
    __bf16* qkv_hi = p;  p += qkvN;
    __bf16* qkv_lo = p;  p += qkvN;
    __bf16* ob_hi  = p;  p += obufN;
    __bf16* ob_lo  = p;  p += obufN;
    __bf16* x_hi   = p;  p += xN;
    __bf16* x_lo   = p;  p += xN;
    __bf16* wq_hi  = p;  p += wqN;
    __bf16* wq_lo  = p;  p += wqN;
    __bf16* wp_hi  = p;  p += wpN;
    __bf16* wp_lo  = p;  p += wpN;
    const size_t NEED_FULL = 2 * (qkvN + obufN + xN + wqN + wpN) * sizeof(__bf16);
    const bool full = ws_size >= NEED_FULL;   // constant per run -> graph-safe

    if (full) {
        split_f32<<<512, 256, 0, stream>>>(x,      x_hi,  x_lo,  (int)(xN / 4));
        split_f32<<<512, 256, 0, stream>>>(w_qkv,  wq_hi, wq_lo, (int)(wqN / 4));
        split_f32<<<256, 256, 0, stream>>>(w_proj, wp_hi, wp_lo, (int)(wpN / 4));
        gemm_nt_mfma<true, true, true, true, false>
            <<<dim3((M / 128) * (3 * DIM / 128)), 256, 0, stream>>>(
            nullptr, x_hi, x_lo, nullptr, wq_hi, wq_lo,
            nullptr, nullptr, qkv_hi, qkv_lo, M, 3 * DIM, DIM);
    } else {
        gemm_nt_mfma<false, false, true, true, false>
            <<<dim3((M / 128) * (3 * DIM / 128)), 256, 0, stream>>>(
            x, nullptr, nullptr, w_qkv, nullptr, nullptr,
            nullptr, nullptr, qkv_hi, qkv_lo, M, 3 * DIM, DIM);
    }

    // 2) fused attention: 512 blocks
    attn_mfma<<<dim3((SEQ / 128) * NHEADS * NB), 256, 0, stream>>>(
        qkv_hi, qkv_lo, ob_hi, ob_lo);

    // 3) output projection + bias
    if (full) {
        gemm_nt_mfma<true, true, false, false, true>
            <<<dim3((M / 128) * (DIM / 128)), 256, 0, stream>>>(
            nullptr, ob_hi, ob_lo, nullptr, wp_hi, wp_lo,
            b_proj, out, nullptr, nullptr, M, DIM, DIM);
    } else {
        gemm_nt_mfma<true, false, false, false, true>
            <<<dim3((M / 128) * (DIM / 128)), 256, 0, stream>>>(
            nullptr, ob_hi, ob_lo, w_proj, nullptr, nullptr,
            b_proj, out, nullptr, nullptr, M, DIM, DIM);
    }
}